// Round 11
// baseline (257.449 us; speedup 1.0000x reference)
//
#include <hip/hip_runtime.h>
#include <hip/hip_bf16.h>
#include <math.h>

#define Bn 4
#define Sn 1024
#define Dn 2048
#define Hn 16
#define DHn 128
#define BS (Bn * Sn)       // 4096
#define QKVC (3 * Dn)      // 6144

typedef __attribute__((ext_vector_type(8))) short short8;     // 8 x bf16
typedef __attribute__((ext_vector_type(4))) float float4v;    // 16x16 acc
typedef __attribute__((ext_vector_type(16))) float float16v;  // 32x32 acc

// f32 -> bf16 (round-to-nearest-even)
__device__ inline unsigned short f2bf(float x) {
  union { float f; unsigned int u; } v; v.f = x;
  unsigned int r = v.u + 0x7fffu + ((v.u >> 16) & 1u);
  return (unsigned short)(r >> 16);
}
__device__ inline float bf2f(unsigned short b) {
  union { unsigned int u; float f; } v; v.u = ((unsigned int)b) << 16;
  return v.f;
}

// async global->LDS, 16B per lane. LDS dest = wave-uniform base + lane*16.
__device__ __forceinline__ void gload16(const unsigned short* g, unsigned short* l) {
  __builtin_amdgcn_global_load_lds(
      (const __attribute__((address_space(1))) unsigned int*)g,
      (__attribute__((address_space(3))) unsigned int*)l, 16, 0, 0);
}

// ---------------------------------------------------------------------------
// Merged prep: x cvt (blocks 0..4095), w_qkv transpose+cvt (4096..7167),
// w_out transpose+cvt (7168..8191). One dispatch instead of three.
// ---------------------------------------------------------------------------
__device__ void tc_body(const float* __restrict__ w, unsigned short* __restrict__ wT,
                        int K, int N, int bx, int by, int tid,
                        unsigned short (*t)[72]) {
  const int c0 = bx * 64;  // N
  const int r0 = by * 64;  // K
  const int r = tid >> 2;
  const int cb = (tid & 3) * 16;
#pragma unroll
  for (int it = 0; it < 4; ++it) {
    float4 v = *reinterpret_cast<const float4*>(&w[(long)(r0 + r) * N + c0 + cb + 4 * it]);
    t[r][cb + 4 * it + 0] = f2bf(v.x);
    t[r][cb + 4 * it + 1] = f2bf(v.y);
    t[r][cb + 4 * it + 2] = f2bf(v.z);
    t[r][cb + 4 * it + 3] = f2bf(v.w);
  }
  __syncthreads();
  unsigned short o[16];
#pragma unroll
  for (int e = 0; e < 16; ++e) o[e] = t[cb + e][r];
  unsigned short* dst = &wT[(long)(c0 + r) * K + r0 + cb];
  *reinterpret_cast<short8*>(dst) = *reinterpret_cast<short8*>(&o[0]);
  *reinterpret_cast<short8*>(dst + 8) = *reinterpret_cast<short8*>(&o[8]);
}

__global__ __launch_bounds__(256) void prep_all(
    const float* __restrict__ x, const float* __restrict__ w_qkv,
    const float* __restrict__ w_out, unsigned short* __restrict__ x16,
    unsigned short* __restrict__ wqkvT, unsigned short* __restrict__ woutT) {
  __shared__ unsigned short t[64][72];
  const int bid = blockIdx.x;
  const int tid = threadIdx.x;
  if (bid < 4096) {
    const int id = bid * 256 + tid;  // 1,048,576 ids x 8 elems
    const float4* p = reinterpret_cast<const float4*>(x) + 2 * (size_t)id;
    float4 a = p[0], b = p[1];
    short8 o;
    o[0] = (short)f2bf(a.x); o[1] = (short)f2bf(a.y);
    o[2] = (short)f2bf(a.z); o[3] = (short)f2bf(a.w);
    o[4] = (short)f2bf(b.x); o[5] = (short)f2bf(b.y);
    o[6] = (short)f2bf(b.z); o[7] = (short)f2bf(b.w);
    *reinterpret_cast<short8*>(x16 + 8 * (size_t)id) = o;
  } else if (bid < 7168) {
    const int lb = bid - 4096;
    tc_body(w_qkv, wqkvT, Dn, QKVC, lb % 96, lb / 96, tid, t);
  } else {
    const int lb = bid - 7168;
    tc_body(w_out, woutT, Dn, Dn, lb % 32, lb / 32, tid, t);
  }
}

// ---------------------------------------------------------------------------
// Shared 256x128-tile pipelined main loop — R8 schedule, 32x32x16 MFMA.
// 512 thr = 8 waves (4M x 2N), 64x64/wave = 2x2 frags of 32x32. BK=64.
// Phase = one k-pair (KH): 8 MFMA, 4 A + 4 B ds_read_b128. Stage slots,
// VMW(2) ledger, barrier count identical to the verified R8 loop.
// Fragment layouts: A/B row|col = lane&31, k = (lane>>5)*8 + e;
// C/D col = lane&31, row = (r&3) + 8*(r>>2) + 4*(lane>>5)  [m74/m101].
// ---------------------------------------------------------------------------
#define AB8(buf, h) ((buf) * 16384 + (h) * 8192)      // shorts
#define BB8(buf) (32768 + (buf) * 8192)               // shorts

#define VMW(n)                                                                 \
  asm volatile("s_waitcnt vmcnt(" #n ")" ::: "memory");                        \
  __builtin_amdgcn_sched_barrier(0);

#define PHASE(BUF, KH, STAGE_STMT, WAIT_STMT)                                  \
  {                                                                            \
    __builtin_amdgcn_sched_barrier(0);                                         \
    short8 afr[2][2], bfr2[2][2];                                              \
    _Pragma("unroll") for (int m2 = 0; m2 < 2; ++m2)                           \
      _Pragma("unroll") for (int kk = 0; kk < 2; ++kk) {                       \
        const int arow = wr * 64 + m2 * 32 + l31;                              \
        const int hh = arow >> 7, rl = arow & 127;                             \
        afr[m2][kk] = *(const short8*)(lds + AB8(BUF, 0) + hh * 8192 +         \
            rl * 64 + ((((KH) * 4 + kk * 2 + hi) ^ w7) << 3));                 \
      }                                                                        \
    _Pragma("unroll") for (int n2 = 0; n2 < 2; ++n2)                           \
      _Pragma("unroll") for (int kk = 0; kk < 2; ++kk) {                       \
        const int brow = wc * 64 + n2 * 32 + l31;                              \
        bfr2[n2][kk] = *(const short8*)(lds + BB8(BUF) + brow * 64 +           \
            ((((KH) * 4 + kk * 2 + hi) ^ w7) << 3));                           \
      }                                                                        \
    STAGE_STMT;                                                                \
    __builtin_amdgcn_sched_barrier(0);                                         \
    __builtin_amdgcn_s_barrier();                                              \
    asm volatile("s_waitcnt lgkmcnt(0)" ::: "memory");                         \
    __builtin_amdgcn_sched_barrier(0);                                         \
    __builtin_amdgcn_s_setprio(1);                                             \
    _Pragma("unroll") for (int kk = 0; kk < 2; ++kk)                           \
      _Pragma("unroll") for (int m2 = 0; m2 < 2; ++m2)                         \
        _Pragma("unroll") for (int n2 = 0; n2 < 2; ++n2)                       \
          acc[m2][n2] = __builtin_amdgcn_mfma_f32_32x32x16_bf16(               \
              afr[m2][kk], bfr2[n2][kk], acc[m2][n2], 0, 0, 0);                \
    __builtin_amdgcn_s_setprio(0);                                             \
    WAIT_STMT                                                                  \
    __builtin_amdgcn_s_barrier();                                              \
  }

#define GEMM_MAIN_LOOP(A_, BT_, K_)                                            \
  STAGE(A_ + (long)m0 * K_, AB8(0, 0));                                        \
  STAGE(A_ + (long)(m0 + 128) * K_, AB8(0, 1));                                \
  STAGE(BT_ + (long)n0 * K_, BB8(0));                                          \
  STAGE(BT_ + (long)n0 * K_ + 64, BB8(1));                                     \
  VMW(2)                                                                       \
  __builtin_amdgcn_s_barrier();                                                \
  for (int it2 = 0; it2 < nt / 2 - 1; ++it2) {                                 \
    const long T1 = (long)(2 * it2 + 1) * 64;                                  \
    const long T2 = (long)(2 * it2 + 2) * 64;                                  \
    const long T3 = (long)(2 * it2 + 3) * 64;                                  \
    PHASE(0, 0, STAGE(A_ + (long)m0 * K_ + T1, AB8(1, 0)), )                   \
    PHASE(0, 1,                                                                \
          { STAGE(A_ + (long)(m0 + 128) * K_ + T1, AB8(1, 1));                 \
            STAGE(BT_ + (long)n0 * K_ + T2, BB8(0)); }, VMW(2))                \
    PHASE(1, 0, STAGE(A_ + (long)m0 * K_ + T2, AB8(0, 0)), )                   \
    PHASE(1, 1,                                                                \
          { STAGE(A_ + (long)(m0 + 128) * K_ + T2, AB8(0, 1));                 \
            STAGE(BT_ + (long)n0 * K_ + T3, BB8(1)); }, VMW(2))                \
  }                                                                            \
  {                                                                            \
    const long TL = (long)(nt - 1) * 64;                                       \
    PHASE(0, 0, STAGE(A_ + (long)m0 * K_ + TL, AB8(1, 0)), )                   \
    PHASE(0, 1, STAGE(A_ + (long)(m0 + 128) * K_ + TL, AB8(1, 1)), VMW(0))     \
    PHASE(1, 0, {}, )                                                          \
    PHASE(1, 1, {}, )                                                          \
  }

// ---------------------------------------------------------------------------
// QKV GEMM with fused rope + head-split + V-transpose epilogue.
// ---------------------------------------------------------------------------
__global__ __launch_bounds__(512, 2) void gemm_qkv(
    const unsigned short* __restrict__ A, const unsigned short* __restrict__ BT,
    const float* __restrict__ rope, const int* __restrict__ tpos,
    unsigned short* __restrict__ qR, unsigned short* __restrict__ kR,
    unsigned short* __restrict__ vT, int K) {
  __shared__ unsigned short lds[49152];  // 96 KiB
  const int tid = threadIdx.x;
  const int wid = tid >> 6, lane = tid & 63;
  const int l31 = lane & 31, hi = lane >> 5, w7 = l31 & 7;
  const int wr = wid >> 1, wc = wid & 1;

  const int nwg = gridDim.x * gridDim.y;
  const int bid = blockIdx.y * gridDim.x + blockIdx.x;
  const int swz = (bid & 7) * (nwg >> 3) + (bid >> 3);
  const int m0 = (swz % gridDim.x) * 256, n0 = (swz / gridDim.x) * 128;

  const int nt = K >> 6;

  float16v acc[2][2];
#pragma unroll
  for (int i = 0; i < 2; ++i)
#pragma unroll
    for (int j = 0; j < 2; ++j)
#pragma unroll
      for (int r = 0; r < 16; ++r) acc[i][j][r] = 0.f;

  auto STAGE = [&](const unsigned short* gbase, int sbase) {
#pragma unroll
    for (int j = 0; j < 2; ++j) {
      const int ch = j * 512 + tid;
      const int r = ch >> 3;
      const int wo = (ch & 7) ^ (r & 7);
      gload16(gbase + (long)r * K + wo * 8, lds + sbase + j * 4096 + wid * 512);
    }
  };

  GEMM_MAIN_LOOP(A, BT, K)

  // ---- fused epilogue (nothing in flight after peeled tail) ----
  const int type = n0 >> 11;            // 0=q 1=k 2=v
  const int h = (n0 & 2047) >> 7;
  const long bh = (long)((m0 >> 10) * Hn + h);
  const int s0 = m0 & 1023;

  if (type == 2) {
    // V: store acc TRANSPOSED into LDS [128 d][264 s], write vT[bh][d][s].
#pragma unroll
    for (int m2 = 0; m2 < 2; ++m2)
#pragma unroll
      for (int n2 = 0; n2 < 2; ++n2)
#pragma unroll
        for (int r = 0; r < 16; ++r) {
          const int mm = wr * 64 + m2 * 32 + (r & 3) + 8 * (r >> 2) + 4 * hi;
          const int nn = wc * 64 + n2 * 32 + l31;
          lds[nn * 264 + mm] = f2bf(acc[m2][n2][r]);
        }
    __syncthreads();
    unsigned short* dst = vT + bh * (long)DHn * Sn + s0;
#pragma unroll
    for (int it = 0; it < 8; ++it) {
      const int cid = it * 512 + tid;
      const int d = cid >> 5;
      const int sl = (cid & 31) * 8;
      short8 v = *reinterpret_cast<const short8*>(lds + d * 264 + sl);
      *reinterpret_cast<short8*>(dst + (long)d * Sn + sl) = v;
    }
  } else {
    // q/k: restage via LDS [256][136], rope pairs lane-local, store wide.
#pragma unroll
    for (int m2 = 0; m2 < 2; ++m2)
#pragma unroll
      for (int n2 = 0; n2 < 2; ++n2)
#pragma unroll
        for (int r = 0; r < 16; ++r) {
          const int mm = wr * 64 + m2 * 32 + (r & 3) + 8 * (r >> 2) + 4 * hi;
          const int nn = wc * 64 + n2 * 32 + l31;
          lds[mm * 136 + nn] = f2bf(acc[m2][n2][r]);
        }
    __syncthreads();
    unsigned short* dst = (type == 0 ? qR : kR) + (bh * Sn + s0) * DHn;
    const float qsc = (type == 0) ? 0.1275174213f : 1.0f;  // log2(e)/sqrt(128)
#pragma unroll
    for (int it = 0; it < 8; ++it) {
      const int cid = it * 512 + tid;
      const int r = cid >> 4;
      const int colc = (cid & 15) * 8;
      union { short8 v; unsigned short u[8]; } iw, ow;
      iw.v = *reinterpret_cast<const short8*>(lds + r * 136 + colc);
      const int pos = tpos[s0 + r];
      const float4* pe = reinterpret_cast<const float4*>(rope) +
                         (long)pos * 64 + (colc >> 1);
#pragma unroll
      for (int p = 0; p < 4; ++p) {
        const float4 m2v = pe[p];
        const float xx = bf2f(iw.u[2 * p]), yy = bf2f(iw.u[2 * p + 1]);
        ow.u[2 * p]     = f2bf((m2v.x * xx + m2v.y * yy) * qsc);
        ow.u[2 * p + 1] = f2bf((m2v.z * xx + m2v.w * yy) * qsc);
      }
      *reinterpret_cast<short8*>(dst + (long)r * DHn + colc) = ow.v;
    }
  }
}

// ---------------------------------------------------------------------------
// Out-proj GEMM (f32 out), same main loop.
// ---------------------------------------------------------------------------
__global__ __launch_bounds__(512, 2) void gemm_out(
    const unsigned short* __restrict__ A, const unsigned short* __restrict__ BT,
    float* __restrict__ Cout, int N, int K) {
  __shared__ unsigned short lds[49152];
  const int tid = threadIdx.x;
  const int wid = tid >> 6, lane = tid & 63;
  const int l31 = lane & 31, hi = lane >> 5, w7 = l31 & 7;
  const int wr = wid >> 1, wc = wid & 1;

  const int nwg = gridDim.x * gridDim.y;
  const int bid = blockIdx.y * gridDim.x + blockIdx.x;
  const int swz = (bid & 7) * (nwg >> 3) + (bid >> 3);
  const int m0 = (swz % gridDim.x) * 256, n0 = (swz / gridDim.x) * 128;

  const int nt = K >> 6;

  float16v acc[2][2];
#pragma unroll
  for (int i = 0; i < 2; ++i)
#pragma unroll
    for (int j = 0; j < 2; ++j)
#pragma unroll
      for (int r = 0; r < 16; ++r) acc[i][j][r] = 0.f;

  auto STAGE = [&](const unsigned short* gbase, int sbase) {
#pragma unroll
    for (int j = 0; j < 2; ++j) {
      const int ch = j * 512 + tid;
      const int r = ch >> 3;
      const int wo = (ch & 7) ^ (r & 7);
      gload16(gbase + (long)r * K + wo * 8, lds + sbase + j * 4096 + wid * 512);
    }
  };

  GEMM_MAIN_LOOP(A, BT, K)

#pragma unroll
  for (int m2 = 0; m2 < 2; ++m2)
#pragma unroll
    for (int n2 = 0; n2 < 2; ++n2)
#pragma unroll
      for (int r = 0; r < 16; ++r) {
        const int mm = wr * 64 + m2 * 32 + (r & 3) + 8 * (r >> 2) + 4 * hi;
        const int nn = wc * 64 + n2 * 32 + l31;
        Cout[(long)(m0 + mm) * N + n0 + nn] = acc[m2][n2][r];
      }
}
#undef PHASE
#undef GEMM_MAIN_LOOP

// ---------------------------------------------------------------------------
// Flash attention v3 (unchanged from R10): 4 waves, KVBLK=64 dbuf, QBLK=128
// via two 64-row q-subtiles sharing each staged K/V tile. 16x16x32 MFMA.
// ---------------------------------------------------------------------------
__global__ __launch_bounds__(256, 2) void attn_mfma(
    const unsigned short* __restrict__ qR, const unsigned short* __restrict__ kR,
    const unsigned short* __restrict__ vTd, unsigned short* __restrict__ ctx) {
  __shared__ unsigned short lds[32768];   // K dbuf @0/8192, V dbuf @16384/24576
  __shared__ unsigned short Ps[4][16][72];
  const int qp = gridDim.x - 1 - blockIdx.x;  // heavy blocks first (LPT)
  const int h = blockIdx.y, b = blockIdx.z;
  const int tid = threadIdx.x, wid = tid >> 6, lane = tid & 63;
  const int c = lane & 15, g = lane >> 4, cg7 = c & 7;
  const long bh = (long)(b * Hn + h);
  const unsigned short* kbase = kR + bh * Sn * DHn;
  const unsigned short* vbase = vTd + bh * DHn * Sn;

  short8 qf[2][4];
#pragma unroll
  for (int sub = 0; sub < 2; ++sub) {
    const unsigned short* qrow =
        qR + (bh * Sn + qp * 128 + sub * 64 + wid * 16 + c) * DHn;
#pragma unroll
    for (int kc = 0; kc < 4; ++kc)
      qf[sub][kc] = *reinterpret_cast<const short8*>(qrow + kc * 32 + g * 8);
  }

  auto STAGE = [&](int kt, int buf) {
#pragma unroll
    for (int j = 0; j < 4; ++j) {  // K tile [64][128]
      const int ch = j * 256 + tid;
      const int r = ch >> 4, wd = ch & 15;
      const int ws = (wd & 8) | ((wd & 7) ^ (r & 7));
      gload16(kbase + (long)kt * 8192 + r * 128 + ws * 8,
              lds + buf * 8192 + j * 2048 + wid * 512);
    }
#pragma unroll
    for (int j = 0; j < 4; ++j) {  // V^T tile [128][64]
      const int ch = j * 256 + tid;
      const int d = ch >> 3, sw = ch & 7;
      gload16(vbase + (long)d * Sn + kt * 64 + ((sw ^ (d & 7)) << 3),
              lds + 16384 + buf * 8192 + j * 2048 + wid * 512);
    }
  };

  float m[2] = {-INFINITY, -INFINITY}, lsum[2] = {0.f, 0.f};
  float4v otA[8], otB[8];
#pragma unroll
  for (int fd = 0; fd < 8; ++fd) {
    otA[fd] = (float4v){0.f, 0.f, 0.f, 0.f};
    otB[fd] = (float4v){0.f, 0.f, 0.f, 0.f};
  }

  const int ntt = 2 * qp + 2;
  STAGE(0, 0);
  __syncthreads();
  int cur = 0;

  for (int kt = 0; kt < ntt; ++kt) {
    if (kt + 1 < ntt) STAGE(kt + 1, cur ^ 1);

#pragma unroll
    for (int sub = 0; sub < 2; ++sub) {
      if (sub == 0 && kt == ntt - 1) continue;
      float4v* ot = (sub == 0) ? otA : otB;

      float4v scv[4];
#pragma unroll
      for (int f = 0; f < 4; ++f) scv[f] = (float4v){0.f, 0.f, 0.f, 0.f};
      __builtin_amdgcn_s_setprio(1);
#pragma unroll
      for (int f = 0; f < 4; ++f)
#pragma unroll
        for (int kc = 0; kc < 4; ++kc) {
          const int wp = kc * 4 + g;
          const int ws = (wp & 8) | ((wp & 7) ^ cg7);
          short8 kf = *reinterpret_cast<const short8*>(
              lds + cur * 8192 + (f * 16 + c) * 128 + ws * 8);
          scv[f] = __builtin_amdgcn_mfma_f32_16x16x32_bf16(kf, qf[sub][kc],
                                                           scv[f], 0, 0, 0);
        }
      __builtin_amdgcn_s_setprio(0);

      if (kt == 2 * qp + sub) {
        const int qloc = wid * 16 + c;
#pragma unroll
        for (int f = 0; f < 4; ++f)
#pragma unroll
          for (int j = 0; j < 4; ++j)
            if (f * 16 + g * 4 + j > qloc) scv[f][j] = -INFINITY;
      }

      float tmax = -INFINITY;
#pragma unroll
      for (int f = 0; f < 4; ++f)
#pragma unroll
        for (int j = 0; j < 4; ++j) tmax = fmaxf(tmax, scv[f][j]);
      tmax = fmaxf(tmax, __shfl_xor(tmax, 16));
      tmax = fmaxf(tmax, __shfl_xor(tmax, 32));

      float mnew, corr;
      if (__all(tmax <= m[sub] + 8.f)) {
        mnew = m[sub]; corr = 1.f;
      } else {
        mnew = fmaxf(m[sub], tmax);
        corr = exp2f(m[sub] - mnew);
#pragma unroll
        for (int fd = 0; fd < 8; ++fd) ot[fd] *= corr;
      }
      float psum = 0.f;
#pragma unroll
      for (int f = 0; f < 4; ++f)
#pragma unroll
        for (int j = 0; j < 4; ++j) {
          scv[f][j] = exp2f(scv[f][j] - mnew);
          psum += scv[f][j];
        }
      psum += __shfl_xor(psum, 16);
      psum += __shfl_xor(psum, 32);
      lsum[sub] = lsum[sub] * corr + psum;
      m[sub] = mnew;

#pragma unroll
      for (int f = 0; f < 4; ++f) {
        unsigned int lo = (unsigned)f2bf(scv[f][0]) | ((unsigned)f2bf(scv[f][1]) << 16);
        unsigned int hi2 = (unsigned)f2bf(scv[f][2]) | ((unsigned)f2bf(scv[f][3]) << 16);
        uint2 pk; pk.x = lo; pk.y = hi2;
        *reinterpret_cast<uint2*>(&Ps[wid][c][f * 16 + g * 4]) = pk;
      }

      short8 pf0 = *reinterpret_cast<const short8*>(&Ps[wid][c][g * 8]);
      short8 pf1 = *reinterpret_cast<const short8*>(&Ps[wid][c][32 + g * 8]);
      __builtin_amdgcn_s_setprio(1);
#pragma unroll
      for (int fd = 0; fd < 8; ++fd) {
        short8 vf0 = *reinterpret_cast<const short8*>(
            lds + 16384 + cur * 8192 + (fd * 16 + c) * 64 + ((g ^ cg7) << 3));
        short8 vf1 = *reinterpret_cast<const short8*>(
            lds + 16384 + cur * 8192 + (fd * 16 + c) * 64 + (((g + 4) ^ cg7) << 3));
        ot[fd] = __builtin_amdgcn_mfma_f32_16x16x32_bf16(vf0, pf0, ot[fd], 0, 0, 0);
        ot[fd] = __builtin_amdgcn_mfma_f32_16x16x32_bf16(vf1, pf1, ot[fd], 0, 0, 0);
      }
      __builtin_amdgcn_s_setprio(0);
    }

    __syncthreads();
    cur ^= 1;
  }

#pragma unroll
  for (int sub = 0; sub < 2; ++sub) {
    const float4v* ot = (sub == 0) ? otA : otB;
    const float inv = 1.0f / lsum[sub];
    unsigned short* orow =
        ctx + (long)(b * Sn + qp * 128 + sub * 64 + wid * 16 + c) * Dn + h * DHn;
#pragma unroll
    for (int fd = 0; fd < 8; ++fd) {
      const int d = fd * 16 + g * 4;
      uint2 pk;
      pk.x = (unsigned)f2bf(ot[fd][0] * inv) | ((unsigned)f2bf(ot[fd][1] * inv) << 16);
      pk.y = (unsigned)f2bf(ot[fd][2] * inv) | ((unsigned)f2bf(ot[fd][3] * inv) << 16);
      *reinterpret_cast<uint2*>(orow + d) = pk;
    }
  }
}

// ---------------------------------------------------------------------------
extern "C" void kernel_launch(void* const* d_in, const int* in_sizes, int n_in,
                              void* d_out, int out_size, void* d_ws, size_t ws_size,
                              hipStream_t stream) {
  const float* x     = (const float*)d_in[0];
  const float* w_qkv = (const float*)d_in[1];
  const float* w_out = (const float*)d_in[2];
  const float* rope  = (const float*)d_in[3];
  const int*   tpos  = (const int*)d_in[4];
  float* out = (float*)d_out;

  unsigned short* x16    = (unsigned short*)d_ws;
  unsigned short* wqkvT  = x16 + (size_t)BS * Dn;
  unsigned short* woutT  = wqkvT + (size_t)Dn * QKVC;
  unsigned short* qR     = woutT + (size_t)Dn * Dn;
  unsigned short* kR     = qR + (size_t)BS * Dn;
  unsigned short* vT16   = kR + (size_t)BS * Dn;
  unsigned short* ctx16  = vT16 + (size_t)BS * Dn;

  prep_all<<<8192, 256, 0, stream>>>(x, w_qkv, w_out, x16, wqkvT, woutT);
  {
    dim3 grid(BS / 256, QKVC / 128);  // 16 x 48 = 768
    gemm_qkv<<<grid, 512, 0, stream>>>(x16, wqkvT, rope, tpos, qR, kR, vT16, Dn);
  }
  {
    dim3 grid(Sn / 128, Hn, Bn);      // 8 x 16 x 4 = 512
    attn_mfma<<<grid, 256, 0, stream>>>(qR, kR, vT16, ctx16);
  }
  {
    dim3 grid(BS / 256, Dn / 128);    // 16 x 16 = 256
    gemm_out<<<grid, 512, 0, stream>>>(ctx16, woutT, out, Dn, Dn);
  }
}

// Round 12
// 250.622 us; speedup vs baseline: 1.0272x; 1.0272x over previous
//
#include <hip/hip_runtime.h>
#include <hip/hip_bf16.h>
#include <math.h>

#define Bn 4
#define Sn 1024
#define Dn 2048
#define Hn 16
#define DHn 128
#define BS (Bn * Sn)       // 4096
#define QKVC (3 * Dn)      // 6144

typedef __attribute__((ext_vector_type(8))) short short8;   // 8 x bf16
typedef __attribute__((ext_vector_type(4))) float float4v;  // MFMA acc

// f32 -> bf16 (round-to-nearest-even)
__device__ inline unsigned short f2bf(float x) {
  union { float f; unsigned int u; } v; v.f = x;
  unsigned int r = v.u + 0x7fffu + ((v.u >> 16) & 1u);
  return (unsigned short)(r >> 16);
}
__device__ inline float bf2f(unsigned short b) {
  union { unsigned int u; float f; } v; v.u = ((unsigned int)b) << 16;
  return v.f;
}

// async global->LDS, 16B per lane. LDS dest = wave-uniform base + lane*16.
__device__ __forceinline__ void gload16(const unsigned short* g, unsigned short* l) {
  __builtin_amdgcn_global_load_lds(
      (const __attribute__((address_space(1))) unsigned int*)g,
      (__attribute__((address_space(3))) unsigned int*)l, 16, 0, 0);
}

// ---------------------------------------------------------------------------
// Merged prep: x cvt (blocks 0..4095), w_qkv transpose+cvt (4096..7167),
// w_out transpose+cvt (7168..8191). One dispatch instead of three.
// ---------------------------------------------------------------------------
__device__ void tc_body(const float* __restrict__ w, unsigned short* __restrict__ wT,
                        int K, int N, int bx, int by, int tid,
                        unsigned short (*t)[72]) {
  const int c0 = bx * 64;  // N
  const int r0 = by * 64;  // K
  const int r = tid >> 2;
  const int cb = (tid & 3) * 16;
#pragma unroll
  for (int it = 0; it < 4; ++it) {
    float4 v = *reinterpret_cast<const float4*>(&w[(long)(r0 + r) * N + c0 + cb + 4 * it]);
    t[r][cb + 4 * it + 0] = f2bf(v.x);
    t[r][cb + 4 * it + 1] = f2bf(v.y);
    t[r][cb + 4 * it + 2] = f2bf(v.z);
    t[r][cb + 4 * it + 3] = f2bf(v.w);
  }
  __syncthreads();
  unsigned short o[16];
#pragma unroll
  for (int e = 0; e < 16; ++e) o[e] = t[cb + e][r];
  unsigned short* dst = &wT[(long)(c0 + r) * K + r0 + cb];
  *reinterpret_cast<short8*>(dst) = *reinterpret_cast<short8*>(&o[0]);
  *reinterpret_cast<short8*>(dst + 8) = *reinterpret_cast<short8*>(&o[8]);
}

__global__ __launch_bounds__(256) void prep_all(
    const float* __restrict__ x, const float* __restrict__ w_qkv,
    const float* __restrict__ w_out, unsigned short* __restrict__ x16,
    unsigned short* __restrict__ wqkvT, unsigned short* __restrict__ woutT) {
  __shared__ unsigned short t[64][72];
  const int bid = blockIdx.x;
  const int tid = threadIdx.x;
  if (bid < 4096) {
    const int id = bid * 256 + tid;  // 1,048,576 ids x 8 elems
    const float4* p = reinterpret_cast<const float4*>(x) + 2 * (size_t)id;
    float4 a = p[0], b = p[1];
    short8 o;
    o[0] = (short)f2bf(a.x); o[1] = (short)f2bf(a.y);
    o[2] = (short)f2bf(a.z); o[3] = (short)f2bf(a.w);
    o[4] = (short)f2bf(b.x); o[5] = (short)f2bf(b.y);
    o[6] = (short)f2bf(b.z); o[7] = (short)f2bf(b.w);
    *reinterpret_cast<short8*>(x16 + 8 * (size_t)id) = o;
  } else if (bid < 7168) {
    const int lb = bid - 4096;
    tc_body(w_qkv, wqkvT, Dn, QKVC, lb % 96, lb / 96, tid, t);
  } else {
    const int lb = bid - 7168;
    tc_body(w_out, woutT, Dn, Dn, lb % 32, lb / 32, tid, t);
  }
}

// ---------------------------------------------------------------------------
// Shared 256x128-tile pipelined main loop (R8-verified, 16x16x32 MFMA).
// 512 thr = 8 waves (4M x 2N), 64x64/wave, BK=64, LDS 96 KiB. Peeled tail:
// nothing in flight after the final barrier.
// ---------------------------------------------------------------------------
#define AB8(buf, h) ((buf) * 16384 + (h) * 8192)      // shorts
#define BB8(buf) (32768 + (buf) * 8192)               // shorts

#define VMW(n)                                                                 \
  asm volatile("s_waitcnt vmcnt(" #n ")" ::: "memory");                        \
  __builtin_amdgcn_sched_barrier(0);

#define PHASE(BUF, MIH, STAGE_STMT, WAIT_STMT)                                 \
  {                                                                            \
    __builtin_amdgcn_sched_barrier(0);                                         \
    short8 afr[2][2];                                                          \
    _Pragma("unroll") for (int mi2 = 0; mi2 < 2; ++mi2) {                      \
      const int mrow = wr * 64 + ((MIH) * 2 + mi2) * 16;                       \
      const int hh = mrow >> 7;                                                \
      const int rl = (mrow & 127) + c;                                         \
      _Pragma("unroll") for (int ks = 0; ks < 2; ++ks)                         \
        afr[mi2][ks] = *(const short8*)(lds + AB8(BUF, 0) + hh * 8192 +        \
            rl * 64 + (((ks * 4 + g) ^ cg7) << 3));                            \
    }                                                                          \
    if ((MIH) == 0) {                                                          \
      _Pragma("unroll") for (int ni = 0; ni < 4; ++ni)                         \
        _Pragma("unroll") for (int ks = 0; ks < 2; ++ks)                       \
          bfr[ni][ks] = *(const short8*)(lds + BB8(BUF) +                      \
              (wc * 64 + ni * 16 + c) * 64 + (((ks * 4 + g) ^ cg7) << 3));     \
    }                                                                          \
    STAGE_STMT;                                                                \
    __builtin_amdgcn_sched_barrier(0);                                         \
    __builtin_amdgcn_s_barrier();                                              \
    asm volatile("s_waitcnt lgkmcnt(0)" ::: "memory");                         \
    __builtin_amdgcn_sched_barrier(0);                                         \
    __builtin_amdgcn_s_setprio(1);                                             \
    _Pragma("unroll") for (int mi2 = 0; mi2 < 2; ++mi2)                        \
      _Pragma("unroll") for (int ni = 0; ni < 4; ++ni)                         \
        _Pragma("unroll") for (int ks = 0; ks < 2; ++ks)                       \
          acc[(MIH) * 2 + mi2][ni] = __builtin_amdgcn_mfma_f32_16x16x32_bf16(  \
              afr[mi2][ks], bfr[ni][ks], acc[(MIH) * 2 + mi2][ni], 0, 0, 0);   \
    __builtin_amdgcn_s_setprio(0);                                             \
    WAIT_STMT                                                                  \
    __builtin_amdgcn_s_barrier();                                              \
  }

#define GEMM_MAIN_LOOP(A_, BT_, K_)                                            \
  STAGE(A_ + (long)m0 * K_, AB8(0, 0));                                        \
  STAGE(A_ + (long)(m0 + 128) * K_, AB8(0, 1));                                \
  STAGE(BT_ + (long)n0 * K_, BB8(0));                                          \
  STAGE(BT_ + (long)n0 * K_ + 64, BB8(1));                                     \
  VMW(2)                                                                       \
  __builtin_amdgcn_s_barrier();                                                \
  for (int it2 = 0; it2 < nt / 2 - 1; ++it2) {                                 \
    const long T1 = (long)(2 * it2 + 1) * 64;                                  \
    const long T2 = (long)(2 * it2 + 2) * 64;                                  \
    const long T3 = (long)(2 * it2 + 3) * 64;                                  \
    PHASE(0, 0, STAGE(A_ + (long)m0 * K_ + T1, AB8(1, 0)), )                   \
    PHASE(0, 1,                                                                \
          { STAGE(A_ + (long)(m0 + 128) * K_ + T1, AB8(1, 1));                 \
            STAGE(BT_ + (long)n0 * K_ + T2, BB8(0)); }, VMW(2))                \
    PHASE(1, 0, STAGE(A_ + (long)m0 * K_ + T2, AB8(0, 0)), )                   \
    PHASE(1, 1,                                                                \
          { STAGE(A_ + (long)(m0 + 128) * K_ + T2, AB8(0, 1));                 \
            STAGE(BT_ + (long)n0 * K_ + T3, BB8(1)); }, VMW(2))                \
  }                                                                            \
  {                                                                            \
    const long TL = (long)(nt - 1) * 64;                                       \
    PHASE(0, 0, STAGE(A_ + (long)m0 * K_ + TL, AB8(1, 0)), )                   \
    PHASE(0, 1, STAGE(A_ + (long)(m0 + 128) * K_ + TL, AB8(1, 1)), VMW(0))     \
    PHASE(1, 0, {}, )                                                          \
    PHASE(1, 1, {}, )                                                          \
  }

// ---------------------------------------------------------------------------
// QKV GEMM with fused rope + head-split + V-transpose epilogue.
// ---------------------------------------------------------------------------
__global__ __launch_bounds__(512, 2) void gemm_qkv(
    const unsigned short* __restrict__ A, const unsigned short* __restrict__ BT,
    const float* __restrict__ rope, const int* __restrict__ tpos,
    unsigned short* __restrict__ qR, unsigned short* __restrict__ kR,
    unsigned short* __restrict__ vT, int K) {
  __shared__ unsigned short lds[49152];  // 96 KiB
  const int tid = threadIdx.x;
  const int wid = tid >> 6, lane = tid & 63;
  const int c = lane & 15, g = lane >> 4;
  const int wr = wid >> 1, wc = wid & 1;
  const int cg7 = c & 7;

  const int nwg = gridDim.x * gridDim.y;
  const int bid = blockIdx.y * gridDim.x + blockIdx.x;
  const int swz = (bid & 7) * (nwg >> 3) + (bid >> 3);
  const int m0 = (swz % gridDim.x) * 256, n0 = (swz / gridDim.x) * 128;

  const int nt = K >> 6;

  float4v acc[4][4];
#pragma unroll
  for (int i = 0; i < 4; ++i)
#pragma unroll
    for (int j = 0; j < 4; ++j) acc[i][j] = (float4v){0.f, 0.f, 0.f, 0.f};
  short8 bfr[4][2];

  auto STAGE = [&](const unsigned short* gbase, int sbase) {
#pragma unroll
    for (int j = 0; j < 2; ++j) {
      const int ch = j * 512 + tid;
      const int r = ch >> 3;
      const int wo = (ch & 7) ^ (r & 7);
      gload16(gbase + (long)r * K + wo * 8, lds + sbase + j * 4096 + wid * 512);
    }
  };

  GEMM_MAIN_LOOP(A, BT, K)

  // ---- fused epilogue (nothing in flight; LDS free after final barrier) ----
  const int type = n0 >> 11;            // 0=q 1=k 2=v
  const int h = (n0 & 2047) >> 7;
  const long bh = (long)((m0 >> 10) * Hn + h);
  const int s0 = m0 & 1023;

  if (type == 2) {
    // V: store acc TRANSPOSED into LDS [128 d][264 s], write vT[bh][d][s].
#pragma unroll
    for (int mi = 0; mi < 4; ++mi)
#pragma unroll
      for (int ni = 0; ni < 4; ++ni)
#pragma unroll
        for (int j = 0; j < 4; ++j) {
          const int mm = wr * 64 + mi * 16 + g * 4 + j;   // s-local
          const int nn = wc * 64 + ni * 16 + c;           // d
          lds[nn * 264 + mm] = f2bf(acc[mi][ni][j]);
        }
    __syncthreads();
    unsigned short* dst = vT + bh * (long)DHn * Sn + s0;
#pragma unroll
    for (int it = 0; it < 8; ++it) {
      const int cid = it * 512 + tid;
      const int d = cid >> 5;
      const int sl = (cid & 31) * 8;
      short8 v = *reinterpret_cast<const short8*>(lds + d * 264 + sl);
      *reinterpret_cast<short8*>(dst + (long)d * Sn + sl) = v;
    }
  } else {
    // q/k: restage via LDS [256][136], rope pairs lane-local, store wide.
#pragma unroll
    for (int mi = 0; mi < 4; ++mi)
#pragma unroll
      for (int ni = 0; ni < 4; ++ni)
#pragma unroll
        for (int j = 0; j < 4; ++j) {
          const int mm = wr * 64 + mi * 16 + g * 4 + j;
          const int nn = wc * 64 + ni * 16 + c;
          lds[mm * 136 + nn] = f2bf(acc[mi][ni][j]);
        }
    __syncthreads();
    unsigned short* dst = (type == 0 ? qR : kR) + (bh * Sn + s0) * DHn;
    const float qsc = (type == 0) ? 0.1275174213f : 1.0f;  // log2(e)/sqrt(128)
#pragma unroll
    for (int it = 0; it < 8; ++it) {
      const int cid = it * 512 + tid;
      const int r = cid >> 4;
      const int colc = (cid & 15) * 8;
      union { short8 v; unsigned short u[8]; } iw, ow;
      iw.v = *reinterpret_cast<const short8*>(lds + r * 136 + colc);
      const int pos = tpos[s0 + r];
      const float4* pe = reinterpret_cast<const float4*>(rope) +
                         (long)pos * 64 + (colc >> 1);
#pragma unroll
      for (int p = 0; p < 4; ++p) {
        const float4 m2 = pe[p];
        const float xx = bf2f(iw.u[2 * p]), yy = bf2f(iw.u[2 * p + 1]);
        ow.u[2 * p]     = f2bf((m2.x * xx + m2.y * yy) * qsc);
        ow.u[2 * p + 1] = f2bf((m2.z * xx + m2.w * yy) * qsc);
      }
      *reinterpret_cast<short8*>(dst + (long)r * DHn + colc) = ow.v;
    }
  }
}

// ---------------------------------------------------------------------------
// Out-proj GEMM (f32 out), same main loop.
// ---------------------------------------------------------------------------
__global__ __launch_bounds__(512, 2) void gemm_out(
    const unsigned short* __restrict__ A, const unsigned short* __restrict__ BT,
    float* __restrict__ Cout, int N, int K) {
  __shared__ unsigned short lds[49152];
  const int tid = threadIdx.x;
  const int wid = tid >> 6, lane = tid & 63;
  const int c = lane & 15, g = lane >> 4;
  const int wr = wid >> 1, wc = wid & 1;
  const int cg7 = c & 7;

  const int nwg = gridDim.x * gridDim.y;
  const int bid = blockIdx.y * gridDim.x + blockIdx.x;
  const int swz = (bid & 7) * (nwg >> 3) + (bid >> 3);
  const int m0 = (swz % gridDim.x) * 256, n0 = (swz / gridDim.x) * 128;

  const int nt = K >> 6;

  float4v acc[4][4];
#pragma unroll
  for (int i = 0; i < 4; ++i)
#pragma unroll
    for (int j = 0; j < 4; ++j) acc[i][j] = (float4v){0.f, 0.f, 0.f, 0.f};
  short8 bfr[4][2];

  auto STAGE = [&](const unsigned short* gbase, int sbase) {
#pragma unroll
    for (int j = 0; j < 2; ++j) {
      const int ch = j * 512 + tid;
      const int r = ch >> 3;
      const int wo = (ch & 7) ^ (r & 7);
      gload16(gbase + (long)r * K + wo * 8, lds + sbase + j * 4096 + wid * 512);
    }
  };

  GEMM_MAIN_LOOP(A, BT, K)

#pragma unroll
  for (int mi = 0; mi < 4; ++mi)
#pragma unroll
    for (int ni = 0; ni < 4; ++ni)
#pragma unroll
      for (int j = 0; j < 4; ++j) {
        const int m = m0 + wr * 64 + mi * 16 + g * 4 + j;
        const int n = n0 + wc * 64 + ni * 16 + c;
        Cout[(long)m * N + n] = acc[mi][ni][j];
      }
}
#undef PHASE
#undef GEMM_MAIN_LOOP

// ---------------------------------------------------------------------------
// Flash attention v3 (R10-verified): 4 waves, KVBLK=64 dbuf, QBLK=128 via
// two 64-row q-subtiles sharing each staged K/V tile.
// ---------------------------------------------------------------------------
__global__ __launch_bounds__(256, 2) void attn_mfma(
    const unsigned short* __restrict__ qR, const unsigned short* __restrict__ kR,
    const unsigned short* __restrict__ vTd, unsigned short* __restrict__ ctx) {
  __shared__ unsigned short lds[32768];   // K dbuf @0/8192, V dbuf @16384/24576
  __shared__ unsigned short Ps[4][16][72];
  const int qp = gridDim.x - 1 - blockIdx.x;  // heavy blocks first (LPT)
  const int h = blockIdx.y, b = blockIdx.z;
  const int tid = threadIdx.x, wid = tid >> 6, lane = tid & 63;
  const int c = lane & 15, g = lane >> 4, cg7 = c & 7;
  const long bh = (long)(b * Hn + h);
  const unsigned short* kbase = kR + bh * Sn * DHn;
  const unsigned short* vbase = vTd + bh * DHn * Sn;

  short8 qf[2][4];
#pragma unroll
  for (int sub = 0; sub < 2; ++sub) {
    const unsigned short* qrow =
        qR + (bh * Sn + qp * 128 + sub * 64 + wid * 16 + c) * DHn;
#pragma unroll
    for (int kc = 0; kc < 4; ++kc)
      qf[sub][kc] = *reinterpret_cast<const short8*>(qrow + kc * 32 + g * 8);
  }

  auto STAGE = [&](int kt, int buf) {
#pragma unroll
    for (int j = 0; j < 4; ++j) {  // K tile [64][128]
      const int ch = j * 256 + tid;
      const int r = ch >> 4, wd = ch & 15;
      const int ws = (wd & 8) | ((wd & 7) ^ (r & 7));
      gload16(kbase + (long)kt * 8192 + r * 128 + ws * 8,
              lds + buf * 8192 + j * 2048 + wid * 512);
    }
#pragma unroll
    for (int j = 0; j < 4; ++j) {  // V^T tile [128][64]
      const int ch = j * 256 + tid;
      const int d = ch >> 3, sw = ch & 7;
      gload16(vbase + (long)d * Sn + kt * 64 + ((sw ^ (d & 7)) << 3),
              lds + 16384 + buf * 8192 + j * 2048 + wid * 512);
    }
  };

  float m[2] = {-INFINITY, -INFINITY}, lsum[2] = {0.f, 0.f};
  float4v otA[8], otB[8];
#pragma unroll
  for (int fd = 0; fd < 8; ++fd) {
    otA[fd] = (float4v){0.f, 0.f, 0.f, 0.f};
    otB[fd] = (float4v){0.f, 0.f, 0.f, 0.f};
  }

  const int ntt = 2 * qp + 2;
  STAGE(0, 0);
  __syncthreads();
  int cur = 0;

  for (int kt = 0; kt < ntt; ++kt) {
    if (kt + 1 < ntt) STAGE(kt + 1, cur ^ 1);

#pragma unroll
    for (int sub = 0; sub < 2; ++sub) {
      if (sub == 0 && kt == ntt - 1) continue;
      float4v* ot = (sub == 0) ? otA : otB;

      float4v scv[4];
#pragma unroll
      for (int f = 0; f < 4; ++f) scv[f] = (float4v){0.f, 0.f, 0.f, 0.f};
      __builtin_amdgcn_s_setprio(1);
#pragma unroll
      for (int f = 0; f < 4; ++f)
#pragma unroll
        for (int kc = 0; kc < 4; ++kc) {
          const int wp = kc * 4 + g;
          const int ws = (wp & 8) | ((wp & 7) ^ cg7);
          short8 kf = *reinterpret_cast<const short8*>(
              lds + cur * 8192 + (f * 16 + c) * 128 + ws * 8);
          scv[f] = __builtin_amdgcn_mfma_f32_16x16x32_bf16(kf, qf[sub][kc],
                                                           scv[f], 0, 0, 0);
        }
      __builtin_amdgcn_s_setprio(0);

      if (kt == 2 * qp + sub) {
        const int qloc = wid * 16 + c;
#pragma unroll
        for (int f = 0; f < 4; ++f)
#pragma unroll
          for (int j = 0; j < 4; ++j)
            if (f * 16 + g * 4 + j > qloc) scv[f][j] = -INFINITY;
      }

      float tmax = -INFINITY;
#pragma unroll
      for (int f = 0; f < 4; ++f)
#pragma unroll
        for (int j = 0; j < 4; ++j) tmax = fmaxf(tmax, scv[f][j]);
      tmax = fmaxf(tmax, __shfl_xor(tmax, 16));
      tmax = fmaxf(tmax, __shfl_xor(tmax, 32));

      float mnew, corr;
      if (__all(tmax <= m[sub] + 8.f)) {  // defer-max
        mnew = m[sub]; corr = 1.f;
      } else {
        mnew = fmaxf(m[sub], tmax);
        corr = exp2f(m[sub] - mnew);
#pragma unroll
        for (int fd = 0; fd < 8; ++fd) ot[fd] *= corr;
      }
      float psum = 0.f;
#pragma unroll
      for (int f = 0; f < 4; ++f)
#pragma unroll
        for (int j = 0; j < 4; ++j) {
          scv[f][j] = exp2f(scv[f][j] - mnew);
          psum += scv[f][j];
        }
      psum += __shfl_xor(psum, 16);
      psum += __shfl_xor(psum, 32);
      lsum[sub] = lsum[sub] * corr + psum;
      m[sub] = mnew;

#pragma unroll
      for (int f = 0; f < 4; ++f) {
        unsigned int lo = (unsigned)f2bf(scv[f][0]) | ((unsigned)f2bf(scv[f][1]) << 16);
        unsigned int hi = (unsigned)f2bf(scv[f][2]) | ((unsigned)f2bf(scv[f][3]) << 16);
        uint2 pk; pk.x = lo; pk.y = hi;
        *reinterpret_cast<uint2*>(&Ps[wid][c][f * 16 + g * 4]) = pk;
      }

      short8 pf0 = *reinterpret_cast<const short8*>(&Ps[wid][c][g * 8]);
      short8 pf1 = *reinterpret_cast<const short8*>(&Ps[wid][c][32 + g * 8]);
      __builtin_amdgcn_s_setprio(1);
#pragma unroll
      for (int fd = 0; fd < 8; ++fd) {
        short8 vf0 = *reinterpret_cast<const short8*>(
            lds + 16384 + cur * 8192 + (fd * 16 + c) * 64 + ((g ^ cg7) << 3));
        short8 vf1 = *reinterpret_cast<const short8*>(
            lds + 16384 + cur * 8192 + (fd * 16 + c) * 64 + (((g + 4) ^ cg7) << 3));
        ot[fd] = __builtin_amdgcn_mfma_f32_16x16x32_bf16(vf0, pf0, ot[fd], 0, 0, 0);
        ot[fd] = __builtin_amdgcn_mfma_f32_16x16x32_bf16(vf1, pf1, ot[fd], 0, 0, 0);
      }
      __builtin_amdgcn_s_setprio(0);
    }

    __syncthreads();
    cur ^= 1;
  }

#pragma unroll
  for (int sub = 0; sub < 2; ++sub) {
    const float4v* ot = (sub == 0) ? otA : otB;
    const float inv = 1.0f / lsum[sub];
    unsigned short* orow =
        ctx + (long)(b * Sn + qp * 128 + sub * 64 + wid * 16 + c) * Dn + h * DHn;
#pragma unroll
    for (int fd = 0; fd < 8; ++fd) {
      const int d = fd * 16 + g * 4;
      uint2 pk;
      pk.x = (unsigned)f2bf(ot[fd][0] * inv) | ((unsigned)f2bf(ot[fd][1] * inv) << 16);
      pk.y = (unsigned)f2bf(ot[fd][2] * inv) | ((unsigned)f2bf(ot[fd][3] * inv) << 16);
      *reinterpret_cast<uint2*>(orow + d) = pk;
    }
  }
}

// ---------------------------------------------------------------------------
extern "C" void kernel_launch(void* const* d_in, const int* in_sizes, int n_in,
                              void* d_out, int out_size, void* d_ws, size_t ws_size,
                              hipStream_t stream) {
  const float* x     = (const float*)d_in[0];
  const float* w_qkv = (const float*)d_in[1];
  const float* w_out = (const float*)d_in[2];
  const float* rope  = (const float*)d_in[3];
  const int*   tpos  = (const int*)d_in[4];
  float* out = (float*)d_out;

  unsigned short* x16    = (unsigned short*)d_ws;
  unsigned short* wqkvT  = x16 + (size_t)BS * Dn;
  unsigned short* woutT  = wqkvT + (size_t)Dn * QKVC;
  unsigned short* qR     = woutT + (size_t)Dn * Dn;
  unsigned short* kR     = qR + (size_t)BS * Dn;
  unsigned short* vT16   = kR + (size_t)BS * Dn;
  unsigned short* ctx16  = vT16 + (size_t)BS * Dn;

  prep_all<<<8192, 256, 0, stream>>>(x, w_qkv, w_out, x16, wqkvT, woutT);
  {
    dim3 grid(BS / 256, QKVC / 128);  // 16 x 48 = 768
    gemm_qkv<<<grid, 512, 0, stream>>>(x16, wqkvT, rope, tpos, qR, kR, vT16, Dn);
  }
  {
    dim3 grid(Sn / 128, Hn, Bn);      // 8 x 16 x 4 = 512
    attn_mfma<<<grid, 256, 0, stream>>>(qR, kR, vT16, ctx16);
  }
  {
    dim3 grid(BS / 256, Dn / 128);    // 16 x 16 = 256
    gemm_out<<<grid, 512, 0, stream>>>(ctx16, woutT, out, Dn, Dn);
  }
}

// Round 13
// 242.854 us; speedup vs baseline: 1.0601x; 1.0320x over previous
//
#include <hip/hip_runtime.h>
#include <hip/hip_bf16.h>
#include <math.h>

#define Bn 4
#define Sn 1024
#define Dn 2048
#define Hn 16
#define DHn 128
#define BS (Bn * Sn)       // 4096
#define QKVC (3 * Dn)      // 6144

typedef __attribute__((ext_vector_type(8))) short short8;   // 8 x bf16
typedef __attribute__((ext_vector_type(4))) float float4v;  // MFMA acc

// f32 -> bf16 (round-to-nearest-even)
__device__ inline unsigned short f2bf(float x) {
  union { float f; unsigned int u; } v; v.f = x;
  unsigned int r = v.u + 0x7fffu + ((v.u >> 16) & 1u);
  return (unsigned short)(r >> 16);
}
__device__ inline float bf2f(unsigned short b) {
  union { unsigned int u; float f; } v; v.u = ((unsigned int)b) << 16;
  return v.f;
}

// async global->LDS, 16B per lane. LDS dest = wave-uniform base + lane*16.
__device__ __forceinline__ void gload16(const unsigned short* g, unsigned short* l) {
  __builtin_amdgcn_global_load_lds(
      (const __attribute__((address_space(1))) unsigned int*)g,
      (__attribute__((address_space(3))) unsigned int*)l, 16, 0, 0);
}

// ---------------------------------------------------------------------------
// Merged prep: x cvt (blocks 0..4095), w_qkv transpose+cvt (4096..7167),
// w_out transpose+cvt (7168..8191).
// ---------------------------------------------------------------------------
__device__ void tc_body(const float* __restrict__ w, unsigned short* __restrict__ wT,
                        int K, int N, int bx, int by, int tid,
                        unsigned short (*t)[72]) {
  const int c0 = bx * 64;  // N
  const int r0 = by * 64;  // K
  const int r = tid >> 2;
  const int cb = (tid & 3) * 16;
#pragma unroll
  for (int it = 0; it < 4; ++it) {
    float4 v = *reinterpret_cast<const float4*>(&w[(long)(r0 + r) * N + c0 + cb + 4 * it]);
    t[r][cb + 4 * it + 0] = f2bf(v.x);
    t[r][cb + 4 * it + 1] = f2bf(v.y);
    t[r][cb + 4 * it + 2] = f2bf(v.z);
    t[r][cb + 4 * it + 3] = f2bf(v.w);
  }
  __syncthreads();
  unsigned short o[16];
#pragma unroll
  for (int e = 0; e < 16; ++e) o[e] = t[cb + e][r];
  unsigned short* dst = &wT[(long)(c0 + r) * K + r0 + cb];
  *reinterpret_cast<short8*>(dst) = *reinterpret_cast<short8*>(&o[0]);
  *reinterpret_cast<short8*>(dst + 8) = *reinterpret_cast<short8*>(&o[8]);
}

__global__ __launch_bounds__(256) void prep_all(
    const float* __restrict__ x, const float* __restrict__ w_qkv,
    const float* __restrict__ w_out, unsigned short* __restrict__ x16,
    unsigned short* __restrict__ wqkvT, unsigned short* __restrict__ woutT) {
  __shared__ unsigned short t[64][72];
  const int bid = blockIdx.x;
  const int tid = threadIdx.x;
  if (bid < 4096) {
    const int id = bid * 256 + tid;
    const float4* p = reinterpret_cast<const float4*>(x) + 2 * (size_t)id;
    float4 a = p[0], b = p[1];
    short8 o;
    o[0] = (short)f2bf(a.x); o[1] = (short)f2bf(a.y);
    o[2] = (short)f2bf(a.z); o[3] = (short)f2bf(a.w);
    o[4] = (short)f2bf(b.x); o[5] = (short)f2bf(b.y);
    o[6] = (short)f2bf(b.z); o[7] = (short)f2bf(b.w);
    *reinterpret_cast<short8*>(x16 + 8 * (size_t)id) = o;
  } else if (bid < 7168) {
    const int lb = bid - 4096;
    tc_body(w_qkv, wqkvT, Dn, QKVC, lb % 96, lb / 96, tid, t);
  } else {
    const int lb = bid - 7168;
    tc_body(w_out, woutT, Dn, Dn, lb % 32, lb / 32, tid, t);
  }
}

// ---------------------------------------------------------------------------
// 128x128-tile GEMM main loop, 256 thr = 4 waves (2M x 2N), 64x64/wave,
// BK=64, LDS 64 KiB (A dbuf 2x16KB + B dbuf 2x16KB) -> 2 blocks/CU.
// m97 2-barrier structure: STAGE(t+1, alt) -> compute(t) -> __syncthreads.
// XOR-window swizzle: chunk (r, w) holds global window w ^ (r&7)
// (inverse-swizzled source + linear gload_lds dest + swizzled ds_read).
// ---------------------------------------------------------------------------
#define ABUF(buf) ((buf) * 8192)              // shorts
#define BBUF(buf) (16384 + (buf) * 8192)      // shorts

#define GEMM128_LOOP(A_, BT_, K_)                                              \
  STAGE(A_ + (long)m0 * K_, ABUF(0));                                          \
  STAGE(BT_ + (long)n0 * K_, BBUF(0));                                         \
  __syncthreads();                                                             \
  for (int t = 0; t < nt; ++t) {                                               \
    const int cb = t & 1;                                                      \
    if (t + 1 < nt) {                                                          \
      const long To = (long)(t + 1) * 64;                                      \
      STAGE(A_ + (long)m0 * K_ + To, ABUF(cb ^ 1));                            \
      STAGE(BT_ + (long)n0 * K_ + To, BBUF(cb ^ 1));                           \
    }                                                                          \
    short8 afr[4][2], bfr[4][2];                                               \
    _Pragma("unroll") for (int mi = 0; mi < 4; ++mi)                           \
      _Pragma("unroll") for (int ks = 0; ks < 2; ++ks)                         \
        afr[mi][ks] = *(const short8*)(lds + ABUF(cb) +                        \
            (wr * 64 + mi * 16 + c) * 64 + (((ks * 4 + g) ^ cg7) << 3));       \
    _Pragma("unroll") for (int ni = 0; ni < 4; ++ni)                           \
      _Pragma("unroll") for (int ks = 0; ks < 2; ++ks)                         \
        bfr[ni][ks] = *(const short8*)(lds + BBUF(cb) +                        \
            (wc * 64 + ni * 16 + c) * 64 + (((ks * 4 + g) ^ cg7) << 3));       \
    __builtin_amdgcn_s_setprio(1);                                             \
    _Pragma("unroll") for (int mi = 0; mi < 4; ++mi)                           \
      _Pragma("unroll") for (int ni = 0; ni < 4; ++ni)                         \
        _Pragma("unroll") for (int ks = 0; ks < 2; ++ks)                       \
          acc[mi][ni] = __builtin_amdgcn_mfma_f32_16x16x32_bf16(               \
              afr[mi][ks], bfr[ni][ks], acc[mi][ni], 0, 0, 0);                 \
    __builtin_amdgcn_s_setprio(0);                                             \
    __syncthreads();                                                           \
  }

// ---------------------------------------------------------------------------
// QKV GEMM with fused rope + head-split + V-transpose epilogue.
// Tile 128x128: n-panel = exactly one head's 128 d's of q, k or v.
// ---------------------------------------------------------------------------
__global__ __launch_bounds__(256, 2) void gemm_qkv(
    const unsigned short* __restrict__ A, const unsigned short* __restrict__ BT,
    const float* __restrict__ rope, const int* __restrict__ tpos,
    unsigned short* __restrict__ qR, unsigned short* __restrict__ kR,
    unsigned short* __restrict__ vT, int K) {
  __shared__ unsigned short lds[32768];  // 64 KiB
  const int tid = threadIdx.x;
  const int wid = tid >> 6, lane = tid & 63;
  const int c = lane & 15, g = lane >> 4;
  const int wr = wid >> 1, wc = wid & 1;
  const int cg7 = c & 7;

  const int nwg = gridDim.x * gridDim.y;
  const int bid = blockIdx.y * gridDim.x + blockIdx.x;
  const int swz = (bid & 7) * (nwg >> 3) + (bid >> 3);
  const int m0 = (swz % gridDim.x) * 128, n0 = (swz / gridDim.x) * 128;

  const int nt = K >> 6;

  float4v acc[4][4];
#pragma unroll
  for (int i = 0; i < 4; ++i)
#pragma unroll
    for (int j = 0; j < 4; ++j) acc[i][j] = (float4v){0.f, 0.f, 0.f, 0.f};

  // stage one [128 rows][64 k] tile; source window inverse-swizzled
  auto STAGE = [&](const unsigned short* gbase, int sbase) {
#pragma unroll
    for (int j = 0; j < 4; ++j) {
      const int ch = j * 256 + tid;     // 0..1023
      const int r = ch >> 3;            // 0..127
      const int wo = (ch & 7) ^ (r & 7);
      gload16(gbase + (long)r * K + wo * 8, lds + sbase + j * 2048 + wid * 512);
    }
  };

  GEMM128_LOOP(A, BT, K)

  // ---- fused epilogue (nothing in flight after final __syncthreads) ----
  const int type = n0 >> 11;            // 0=q 1=k 2=v
  const int h = (n0 & 2047) >> 7;
  const long bh = (long)((m0 >> 10) * Hn + h);
  const int s0 = m0 & 1023;

  if (type == 2) {
    // V: store acc TRANSPOSED into LDS [128 d][136 s], write vT[bh][d][s].
#pragma unroll
    for (int mi = 0; mi < 4; ++mi)
#pragma unroll
      for (int ni = 0; ni < 4; ++ni)
#pragma unroll
        for (int j = 0; j < 4; ++j) {
          const int mm = wr * 64 + mi * 16 + g * 4 + j;   // s-local
          const int nn = wc * 64 + ni * 16 + c;           // d
          lds[nn * 136 + mm] = f2bf(acc[mi][ni][j]);
        }
    __syncthreads();
    unsigned short* dst = vT + bh * (long)DHn * Sn + s0;
#pragma unroll
    for (int it = 0; it < 8; ++it) {
      const int cid = it * 256 + tid;
      const int d = cid >> 4;            // 0..127
      const int sl = (cid & 15) * 8;     // 0..120
      short8 v = *reinterpret_cast<const short8*>(lds + d * 136 + sl);
      *reinterpret_cast<short8*>(dst + (long)d * Sn + sl) = v;
    }
  } else {
    // q/k: restage via LDS [128][136], rope pairs lane-local, store wide.
#pragma unroll
    for (int mi = 0; mi < 4; ++mi)
#pragma unroll
      for (int ni = 0; ni < 4; ++ni)
#pragma unroll
        for (int j = 0; j < 4; ++j) {
          const int mm = wr * 64 + mi * 16 + g * 4 + j;
          const int nn = wc * 64 + ni * 16 + c;
          lds[mm * 136 + nn] = f2bf(acc[mi][ni][j]);
        }
    __syncthreads();
    unsigned short* dst = (type == 0 ? qR : kR) + (bh * Sn + s0) * DHn;
    const float qsc = (type == 0) ? 0.1275174213f : 1.0f;  // log2(e)/sqrt(128)
#pragma unroll
    for (int it = 0; it < 8; ++it) {
      const int cid = it * 256 + tid;
      const int r = cid >> 4;            // 0..127 (s-local)
      const int colc = (cid & 15) * 8;   // 0..120 (d)
      union { short8 v; unsigned short u[8]; } iw, ow;
      iw.v = *reinterpret_cast<const short8*>(lds + r * 136 + colc);
      const int pos = tpos[s0 + r];
      const float4* pe = reinterpret_cast<const float4*>(rope) +
                         (long)pos * 64 + (colc >> 1);
#pragma unroll
      for (int p = 0; p < 4; ++p) {
        const float4 m2 = pe[p];
        const float xx = bf2f(iw.u[2 * p]), yy = bf2f(iw.u[2 * p + 1]);
        ow.u[2 * p]     = f2bf((m2.x * xx + m2.y * yy) * qsc);
        ow.u[2 * p + 1] = f2bf((m2.z * xx + m2.w * yy) * qsc);
      }
      *reinterpret_cast<short8*>(dst + (long)r * DHn + colc) = ow.v;
    }
  }
}

// ---------------------------------------------------------------------------
// Out-proj GEMM (f32 out), same 128x128 main loop.
// ---------------------------------------------------------------------------
__global__ __launch_bounds__(256, 2) void gemm_out(
    const unsigned short* __restrict__ A, const unsigned short* __restrict__ BT,
    float* __restrict__ Cout, int N, int K) {
  __shared__ unsigned short lds[32768];
  const int tid = threadIdx.x;
  const int wid = tid >> 6, lane = tid & 63;
  const int c = lane & 15, g = lane >> 4;
  const int wr = wid >> 1, wc = wid & 1;
  const int cg7 = c & 7;

  const int nwg = gridDim.x * gridDim.y;
  const int bid = blockIdx.y * gridDim.x + blockIdx.x;
  const int swz = (bid & 7) * (nwg >> 3) + (bid >> 3);
  const int m0 = (swz % gridDim.x) * 128, n0 = (swz / gridDim.x) * 128;

  const int nt = K >> 6;

  float4v acc[4][4];
#pragma unroll
  for (int i = 0; i < 4; ++i)
#pragma unroll
    for (int j = 0; j < 4; ++j) acc[i][j] = (float4v){0.f, 0.f, 0.f, 0.f};

  auto STAGE = [&](const unsigned short* gbase, int sbase) {
#pragma unroll
    for (int j = 0; j < 4; ++j) {
      const int ch = j * 256 + tid;
      const int r = ch >> 3;
      const int wo = (ch & 7) ^ (r & 7);
      gload16(gbase + (long)r * K + wo * 8, lds + sbase + j * 2048 + wid * 512);
    }
  };

  GEMM128_LOOP(A, BT, K)

#pragma unroll
  for (int mi = 0; mi < 4; ++mi)
#pragma unroll
    for (int ni = 0; ni < 4; ++ni)
#pragma unroll
      for (int j = 0; j < 4; ++j) {
        const int m = m0 + wr * 64 + mi * 16 + g * 4 + j;
        const int n = n0 + wc * 64 + ni * 16 + c;
        Cout[(long)m * N + n] = acc[mi][ni][j];
      }
}
#undef GEMM128_LOOP

// ---------------------------------------------------------------------------
// Flash attention v3 (R10-verified, unchanged): 4 waves, KVBLK=64 dbuf,
// QBLK=128 via two 64-row q-subtiles sharing each staged K/V tile.
// ---------------------------------------------------------------------------
__global__ __launch_bounds__(256, 2) void attn_mfma(
    const unsigned short* __restrict__ qR, const unsigned short* __restrict__ kR,
    const unsigned short* __restrict__ vTd, unsigned short* __restrict__ ctx) {
  __shared__ unsigned short lds[32768];   // K dbuf @0/8192, V dbuf @16384/24576
  __shared__ unsigned short Ps[4][16][72];
  const int qp = gridDim.x - 1 - blockIdx.x;  // heavy blocks first (LPT)
  const int h = blockIdx.y, b = blockIdx.z;
  const int tid = threadIdx.x, wid = tid >> 6, lane = tid & 63;
  const int c = lane & 15, g = lane >> 4, cg7 = c & 7;
  const long bh = (long)(b * Hn + h);
  const unsigned short* kbase = kR + bh * Sn * DHn;
  const unsigned short* vbase = vTd + bh * DHn * Sn;

  short8 qf[2][4];
#pragma unroll
  for (int sub = 0; sub < 2; ++sub) {
    const unsigned short* qrow =
        qR + (bh * Sn + qp * 128 + sub * 64 + wid * 16 + c) * DHn;
#pragma unroll
    for (int kc = 0; kc < 4; ++kc)
      qf[sub][kc] = *reinterpret_cast<const short8*>(qrow + kc * 32 + g * 8);
  }

  auto STAGE = [&](int kt, int buf) {
#pragma unroll
    for (int j = 0; j < 4; ++j) {  // K tile [64][128]
      const int ch = j * 256 + tid;
      const int r = ch >> 4, wd = ch & 15;
      const int ws = (wd & 8) | ((wd & 7) ^ (r & 7));
      gload16(kbase + (long)kt * 8192 + r * 128 + ws * 8,
              lds + buf * 8192 + j * 2048 + wid * 512);
    }
#pragma unroll
    for (int j = 0; j < 4; ++j) {  // V^T tile [128][64]
      const int ch = j * 256 + tid;
      const int d = ch >> 3, sw = ch & 7;
      gload16(vbase + (long)d * Sn + kt * 64 + ((sw ^ (d & 7)) << 3),
              lds + 16384 + buf * 8192 + j * 2048 + wid * 512);
    }
  };

  float m[2] = {-INFINITY, -INFINITY}, lsum[2] = {0.f, 0.f};
  float4v otA[8], otB[8];
#pragma unroll
  for (int fd = 0; fd < 8; ++fd) {
    otA[fd] = (float4v){0.f, 0.f, 0.f, 0.f};
    otB[fd] = (float4v){0.f, 0.f, 0.f, 0.f};
  }

  const int ntt = 2 * qp + 2;
  STAGE(0, 0);
  __syncthreads();
  int cur = 0;

  for (int kt = 0; kt < ntt; ++kt) {
    if (kt + 1 < ntt) STAGE(kt + 1, cur ^ 1);

#pragma unroll
    for (int sub = 0; sub < 2; ++sub) {
      if (sub == 0 && kt == ntt - 1) continue;
      float4v* ot = (sub == 0) ? otA : otB;

      float4v scv[4];
#pragma unroll
      for (int f = 0; f < 4; ++f) scv[f] = (float4v){0.f, 0.f, 0.f, 0.f};
      __builtin_amdgcn_s_setprio(1);
#pragma unroll
      for (int f = 0; f < 4; ++f)
#pragma unroll
        for (int kc = 0; kc < 4; ++kc) {
          const int wp = kc * 4 + g;
          const int ws = (wp & 8) | ((wp & 7) ^ cg7);
          short8 kf = *reinterpret_cast<const short8*>(
              lds + cur * 8192 + (f * 16 + c) * 128 + ws * 8);
          scv[f] = __builtin_amdgcn_mfma_f32_16x16x32_bf16(kf, qf[sub][kc],
                                                           scv[f], 0, 0, 0);
        }
      __builtin_amdgcn_s_setprio(0);

      if (kt == 2 * qp + sub) {
        const int qloc = wid * 16 + c;
#pragma unroll
        for (int f = 0; f < 4; ++f)
#pragma unroll
          for (int j = 0; j < 4; ++j)
            if (f * 16 + g * 4 + j > qloc) scv[f][j] = -INFINITY;
      }

      float tmax = -INFINITY;
#pragma unroll
      for (int f = 0; f < 4; ++f)
#pragma unroll
        for (int j = 0; j < 4; ++j) tmax = fmaxf(tmax, scv[f][j]);
      tmax = fmaxf(tmax, __shfl_xor(tmax, 16));
      tmax = fmaxf(tmax, __shfl_xor(tmax, 32));

      float mnew, corr;
      if (__all(tmax <= m[sub] + 8.f)) {  // defer-max
        mnew = m[sub]; corr = 1.f;
      } else {
        mnew = fmaxf(m[sub], tmax);
        corr = exp2f(m[sub] - mnew);
#pragma unroll
        for (int fd = 0; fd < 8; ++fd) ot[fd] *= corr;
      }
      float psum = 0.f;
#pragma unroll
      for (int f = 0; f < 4; ++f)
#pragma unroll
        for (int j = 0; j < 4; ++j) {
          scv[f][j] = exp2f(scv[f][j] - mnew);
          psum += scv[f][j];
        }
      psum += __shfl_xor(psum, 16);
      psum += __shfl_xor(psum, 32);
      lsum[sub] = lsum[sub] * corr + psum;
      m[sub] = mnew;

#pragma unroll
      for (int f = 0; f < 4; ++f) {
        unsigned int lo = (unsigned)f2bf(scv[f][0]) | ((unsigned)f2bf(scv[f][1]) << 16);
        unsigned int hi = (unsigned)f2bf(scv[f][2]) | ((unsigned)f2bf(scv[f][3]) << 16);
        uint2 pk; pk.x = lo; pk.y = hi;
        *reinterpret_cast<uint2*>(&Ps[wid][c][f * 16 + g * 4]) = pk;
      }

      short8 pf0 = *reinterpret_cast<const short8*>(&Ps[wid][c][g * 8]);
      short8 pf1 = *reinterpret_cast<const short8*>(&Ps[wid][c][32 + g * 8]);
      __builtin_amdgcn_s_setprio(1);
#pragma unroll
      for (int fd = 0; fd < 8; ++fd) {
        short8 vf0 = *reinterpret_cast<const short8*>(
            lds + 16384 + cur * 8192 + (fd * 16 + c) * 64 + ((g ^ cg7) << 3));
        short8 vf1 = *reinterpret_cast<const short8*>(
            lds + 16384 + cur * 8192 + (fd * 16 + c) * 64 + (((g + 4) ^ cg7) << 3));
        ot[fd] = __builtin_amdgcn_mfma_f32_16x16x32_bf16(vf0, pf0, ot[fd], 0, 0, 0);
        ot[fd] = __builtin_amdgcn_mfma_f32_16x16x32_bf16(vf1, pf1, ot[fd], 0, 0, 0);
      }
      __builtin_amdgcn_s_setprio(0);
    }

    __syncthreads();
    cur ^= 1;
  }

#pragma unroll
  for (int sub = 0; sub < 2; ++sub) {
    const float4v* ot = (sub == 0) ? otA : otB;
    const float inv = 1.0f / lsum[sub];
    unsigned short* orow =
        ctx + (long)(b * Sn + qp * 128 + sub * 64 + wid * 16 + c) * Dn + h * DHn;
#pragma unroll
    for (int fd = 0; fd < 8; ++fd) {
      const int d = fd * 16 + g * 4;
      uint2 pk;
      pk.x = (unsigned)f2bf(ot[fd][0] * inv) | ((unsigned)f2bf(ot[fd][1] * inv) << 16);
      pk.y = (unsigned)f2bf(ot[fd][2] * inv) | ((unsigned)f2bf(ot[fd][3] * inv) << 16);
      *reinterpret_cast<uint2*>(orow + d) = pk;
    }
  }
}

// ---------------------------------------------------------------------------
extern "C" void kernel_launch(void* const* d_in, const int* in_sizes, int n_in,
                              void* d_out, int out_size, void* d_ws, size_t ws_size,
                              hipStream_t stream) {
  const float* x     = (const float*)d_in[0];
  const float* w_qkv = (const float*)d_in[1];
  const float* w_out = (const float*)d_in[2];
  const float* rope  = (const float*)d_in[3];
  const int*   tpos  = (const int*)d_in[4];
  float* out = (float*)d_out;

  unsigned short* x16    = (unsigned short*)d_ws;
  unsigned short* wqkvT  = x16 + (size_t)BS * Dn;
  unsigned short* woutT  = wqkvT + (size_t)Dn * QKVC;
  unsigned short* qR     = woutT + (size_t)Dn * Dn;
  unsigned short* kR     = qR + (size_t)BS * Dn;
  unsigned short* vT16   = kR + (size_t)BS * Dn;
  unsigned short* ctx16  = vT16 + (size_t)BS * Dn;

  prep_all<<<8192, 256, 0, stream>>>(x, w_qkv, w_out, x16, wqkvT, woutT);
  {
    dim3 grid(BS / 128, QKVC / 128);  // 32 x 48 = 1536 = 3.0 rounds @ 2/CU
    gemm_qkv<<<grid, 256, 0, stream>>>(x16, wqkvT, rope, tpos, qR, kR, vT16, Dn);
  }
  {
    dim3 grid(Sn / 128, Hn, Bn);      // 8 x 16 x 4 = 512
    attn_mfma<<<grid, 256, 0, stream>>>(qR, kR, vT16, ctx16);
  }
  {
    dim3 grid(BS / 128, Dn / 128);    // 32 x 16 = 512 = 1.0 round @ 2/CU
    gemm_out<<<grid, 256, 0, stream>>>(ctx16, woutT, out, Dn, Dn);
  }
}

// Round 14
// 210.025 us; speedup vs baseline: 1.2258x; 1.1563x over previous
//
#include <hip/hip_runtime.h>
#include <hip/hip_bf16.h>
#include <math.h>

#define Bn 4
#define Sn 1024
#define Dn 2048
#define Hn 16
#define DHn 128
#define BS (Bn * Sn)       // 4096
#define QKVC (3 * Dn)      // 6144

typedef __attribute__((ext_vector_type(8))) short short8;   // 8 x bf16
typedef __attribute__((ext_vector_type(4))) float float4v;  // MFMA acc

// f32 -> bf16 (round-to-nearest-even)
__device__ inline unsigned short f2bf(float x) {
  union { float f; unsigned int u; } v; v.f = x;
  unsigned int r = v.u + 0x7fffu + ((v.u >> 16) & 1u);
  return (unsigned short)(r >> 16);
}
__device__ inline float bf2f(unsigned short b) {
  union { unsigned int u; float f; } v; v.u = ((unsigned int)b) << 16;
  return v.f;
}

// async global->LDS, 16B per lane. LDS dest = wave-uniform base + lane*16.
__device__ __forceinline__ void gload16(const unsigned short* g, unsigned short* l) {
  __builtin_amdgcn_global_load_lds(
      (const __attribute__((address_space(1))) unsigned int*)g,
      (__attribute__((address_space(3))) unsigned int*)l, 16, 0, 0);
}

// ---------------------------------------------------------------------------
// Merged prep: x cvt (blocks 0..4095), w_qkv transpose+cvt (4096..7167),
// w_out transpose+cvt (7168..8191).
// ---------------------------------------------------------------------------
__device__ void tc_body(const float* __restrict__ w, unsigned short* __restrict__ wT,
                        int K, int N, int bx, int by, int tid,
                        unsigned short (*t)[72]) {
  const int c0 = bx * 64;  // N
  const int r0 = by * 64;  // K
  const int r = tid >> 2;
  const int cb = (tid & 3) * 16;
#pragma unroll
  for (int it = 0; it < 4; ++it) {
    float4 v = *reinterpret_cast<const float4*>(&w[(long)(r0 + r) * N + c0 + cb + 4 * it]);
    t[r][cb + 4 * it + 0] = f2bf(v.x);
    t[r][cb + 4 * it + 1] = f2bf(v.y);
    t[r][cb + 4 * it + 2] = f2bf(v.z);
    t[r][cb + 4 * it + 3] = f2bf(v.w);
  }
  __syncthreads();
  unsigned short o[16];
#pragma unroll
  for (int e = 0; e < 16; ++e) o[e] = t[cb + e][r];
  unsigned short* dst = &wT[(long)(c0 + r) * K + r0 + cb];
  *reinterpret_cast<short8*>(dst) = *reinterpret_cast<short8*>(&o[0]);
  *reinterpret_cast<short8*>(dst + 8) = *reinterpret_cast<short8*>(&o[8]);
}

__global__ __launch_bounds__(256) void prep_all(
    const float* __restrict__ x, const float* __restrict__ w_qkv,
    const float* __restrict__ w_out, unsigned short* __restrict__ x16,
    unsigned short* __restrict__ wqkvT, unsigned short* __restrict__ woutT) {
  __shared__ unsigned short t[64][72];
  const int bid = blockIdx.x;
  const int tid = threadIdx.x;
  if (bid < 4096) {
    const int id = bid * 256 + tid;
    const float4* p = reinterpret_cast<const float4*>(x) + 2 * (size_t)id;
    float4 a = p[0], b = p[1];
    short8 o;
    o[0] = (short)f2bf(a.x); o[1] = (short)f2bf(a.y);
    o[2] = (short)f2bf(a.z); o[3] = (short)f2bf(a.w);
    o[4] = (short)f2bf(b.x); o[5] = (short)f2bf(b.y);
    o[6] = (short)f2bf(b.z); o[7] = (short)f2bf(b.w);
    *reinterpret_cast<short8*>(x16 + 8 * (size_t)id) = o;
  } else if (bid < 7168) {
    const int lb = bid - 4096;
    tc_body(w_qkv, wqkvT, Dn, QKVC, lb % 96, lb / 96, tid, t);
  } else {
    const int lb = bid - 7168;
    tc_body(w_out, woutT, Dn, Dn, lb % 32, lb / 32, tid, t);
  }
}

// ---------------------------------------------------------------------------
// 128x128-tile GEMM main loop, 256 thr = 4 waves (2M x 2N), 64x64/wave,
// BK=64, LDS 64 KiB dbuf -> 2 blocks/CU. m97 2-barrier structure.
// Tile mapping: XCD spread + group-of-8-n inner ordering (8 blocks share an
// A tile back-to-back; 8 B panels = 4 MB stay L2-resident per group).
// ---------------------------------------------------------------------------
#define ABUF(buf) ((buf) * 8192)              // shorts
#define BBUF(buf) (16384 + (buf) * 8192)      // shorts

#define TILE_MAP()                                                             \
  const int nwg = gridDim.x * gridDim.y;                                       \
  const int bid = blockIdx.y * gridDim.x + blockIdx.x;                         \
  const int swz = (bid & 7) * (nwg >> 3) + (bid >> 3);                         \
  const int t_ = swz & 255, grp_ = swz >> 8;                                   \
  const int m0 = (t_ >> 3) * 128;                                              \
  const int n0 = ((t_ & 7) + grp_ * 8) * 128;

#define GEMM128_LOOP(A_, BT_, K_)                                              \
  STAGE(A_ + (long)m0 * K_, ABUF(0));                                          \
  STAGE(BT_ + (long)n0 * K_, BBUF(0));                                         \
  __syncthreads();                                                             \
  for (int t = 0; t < nt; ++t) {                                               \
    const int cb = t & 1;                                                      \
    if (t + 1 < nt) {                                                          \
      const long To = (long)(t + 1) * 64;                                      \
      STAGE(A_ + (long)m0 * K_ + To, ABUF(cb ^ 1));                            \
      STAGE(BT_ + (long)n0 * K_ + To, BBUF(cb ^ 1));                           \
    }                                                                          \
    short8 afr[4][2], bfr[4][2];                                               \
    _Pragma("unroll") for (int mi = 0; mi < 4; ++mi)                           \
      _Pragma("unroll") for (int ks = 0; ks < 2; ++ks)                         \
        afr[mi][ks] = *(const short8*)(lds + ABUF(cb) +                        \
            (wr * 64 + mi * 16 + c) * 64 + (((ks * 4 + g) ^ cg7) << 3));       \
    _Pragma("unroll") for (int ni = 0; ni < 4; ++ni)                           \
      _Pragma("unroll") for (int ks = 0; ks < 2; ++ks)                         \
        bfr[ni][ks] = *(const short8*)(lds + BBUF(cb) +                        \
            (wc * 64 + ni * 16 + c) * 64 + (((ks * 4 + g) ^ cg7) << 3));       \
    __builtin_amdgcn_s_setprio(1);                                             \
    _Pragma("unroll") for (int mi = 0; mi < 4; ++mi)                           \
      _Pragma("unroll") for (int ni = 0; ni < 4; ++ni)                         \
        _Pragma("unroll") for (int ks = 0; ks < 2; ++ks)                       \
          acc[mi][ni] = __builtin_amdgcn_mfma_f32_16x16x32_bf16(               \
              afr[mi][ks], bfr[ni][ks], acc[mi][ni], 0, 0, 0);                 \
    __builtin_amdgcn_s_setprio(0);                                             \
    __syncthreads();                                                           \
  }

// ---------------------------------------------------------------------------
// QKV GEMM with fused rope + head-split + V-transpose epilogue.
// ---------------------------------------------------------------------------
__global__ __launch_bounds__(256, 2) void gemm_qkv(
    const unsigned short* __restrict__ A, const unsigned short* __restrict__ BT,
    const float* __restrict__ rope, const int* __restrict__ tpos,
    unsigned short* __restrict__ qR, unsigned short* __restrict__ kR,
    unsigned short* __restrict__ vT, int K) {
  __shared__ unsigned short lds[32768];  // 64 KiB
  const int tid = threadIdx.x;
  const int wid = tid >> 6, lane = tid & 63;
  const int c = lane & 15, g = lane >> 4;
  const int wr = wid >> 1, wc = wid & 1;
  const int cg7 = c & 7;

  TILE_MAP()

  const int nt = K >> 6;

  float4v acc[4][4];
#pragma unroll
  for (int i = 0; i < 4; ++i)
#pragma unroll
    for (int j = 0; j < 4; ++j) acc[i][j] = (float4v){0.f, 0.f, 0.f, 0.f};

  auto STAGE = [&](const unsigned short* gbase, int sbase) {
#pragma unroll
    for (int j = 0; j < 4; ++j) {
      const int ch = j * 256 + tid;     // 0..1023
      const int r = ch >> 3;            // 0..127
      const int wo = (ch & 7) ^ (r & 7);
      gload16(gbase + (long)r * K + wo * 8, lds + sbase + j * 2048 + wid * 512);
    }
  };

  GEMM128_LOOP(A, BT, K)

  // ---- fused epilogue ----
  const int type = n0 >> 11;            // 0=q 1=k 2=v
  const int h = (n0 & 2047) >> 7;
  const long bh = (long)((m0 >> 10) * Hn + h);
  const int s0 = m0 & 1023;

  if (type == 2) {
#pragma unroll
    for (int mi = 0; mi < 4; ++mi)
#pragma unroll
      for (int ni = 0; ni < 4; ++ni)
#pragma unroll
        for (int j = 0; j < 4; ++j) {
          const int mm = wr * 64 + mi * 16 + g * 4 + j;   // s-local
          const int nn = wc * 64 + ni * 16 + c;           // d
          lds[nn * 136 + mm] = f2bf(acc[mi][ni][j]);
        }
    __syncthreads();
    unsigned short* dst = vT + bh * (long)DHn * Sn + s0;
#pragma unroll
    for (int it = 0; it < 8; ++it) {
      const int cid = it * 256 + tid;
      const int d = cid >> 4;
      const int sl = (cid & 15) * 8;
      short8 v = *reinterpret_cast<const short8*>(lds + d * 136 + sl);
      *reinterpret_cast<short8*>(dst + (long)d * Sn + sl) = v;
    }
  } else {
#pragma unroll
    for (int mi = 0; mi < 4; ++mi)
#pragma unroll
      for (int ni = 0; ni < 4; ++ni)
#pragma unroll
        for (int j = 0; j < 4; ++j) {
          const int mm = wr * 64 + mi * 16 + g * 4 + j;
          const int nn = wc * 64 + ni * 16 + c;
          lds[mm * 136 + nn] = f2bf(acc[mi][ni][j]);
        }
    __syncthreads();
    unsigned short* dst = (type == 0 ? qR : kR) + (bh * Sn + s0) * DHn;
    const float qsc = (type == 0) ? 0.1275174213f : 1.0f;  // log2(e)/sqrt(128)
#pragma unroll
    for (int it = 0; it < 8; ++it) {
      const int cid = it * 256 + tid;
      const int r = cid >> 4;
      const int colc = (cid & 15) * 8;
      union { short8 v; unsigned short u[8]; } iw, ow;
      iw.v = *reinterpret_cast<const short8*>(lds + r * 136 + colc);
      const int pos = tpos[s0 + r];
      const float4* pe = reinterpret_cast<const float4*>(rope) +
                         (long)pos * 64 + (colc >> 1);
#pragma unroll
      for (int p = 0; p < 4; ++p) {
        const float4 m2 = pe[p];
        const float xx = bf2f(iw.u[2 * p]), yy = bf2f(iw.u[2 * p + 1]);
        ow.u[2 * p]     = f2bf((m2.x * xx + m2.y * yy) * qsc);
        ow.u[2 * p + 1] = f2bf((m2.z * xx + m2.w * yy) * qsc);
      }
      *reinterpret_cast<short8*>(dst + (long)r * DHn + colc) = ow.v;
    }
  }
}

// ---------------------------------------------------------------------------
// Out-proj GEMM (f32 out), same 128x128 main loop.
// ---------------------------------------------------------------------------
__global__ __launch_bounds__(256, 2) void gemm_out(
    const unsigned short* __restrict__ A, const unsigned short* __restrict__ BT,
    float* __restrict__ Cout, int N, int K) {
  __shared__ unsigned short lds[32768];
  const int tid = threadIdx.x;
  const int wid = tid >> 6, lane = tid & 63;
  const int c = lane & 15, g = lane >> 4;
  const int wr = wid >> 1, wc = wid & 1;
  const int cg7 = c & 7;

  TILE_MAP()

  const int nt = K >> 6;

  float4v acc[4][4];
#pragma unroll
  for (int i = 0; i < 4; ++i)
#pragma unroll
    for (int j = 0; j < 4; ++j) acc[i][j] = (float4v){0.f, 0.f, 0.f, 0.f};

  auto STAGE = [&](const unsigned short* gbase, int sbase) {
#pragma unroll
    for (int j = 0; j < 4; ++j) {
      const int ch = j * 256 + tid;
      const int r = ch >> 3;
      const int wo = (ch & 7) ^ (r & 7);
      gload16(gbase + (long)r * K + wo * 8, lds + sbase + j * 2048 + wid * 512);
    }
  };

  GEMM128_LOOP(A, BT, K)

#pragma unroll
  for (int mi = 0; mi < 4; ++mi)
#pragma unroll
    for (int ni = 0; ni < 4; ++ni)
#pragma unroll
      for (int j = 0; j < 4; ++j) {
        const int m = m0 + wr * 64 + mi * 16 + g * 4 + j;
        const int n = n0 + wc * 64 + ni * 16 + c;
        Cout[(long)m * N + n] = acc[mi][ni][j];
      }
}
#undef GEMM128_LOOP
#undef TILE_MAP

// ---------------------------------------------------------------------------
// Flash attention v4: v3 body with CU-balanced block scheduling.
// 1-D grid 512: blocks 0..255 heavy (qp 7,6,5,4), 256..511 light (qp 0,1,2,3)
// -> round-robin block->CU assignment pairs heavy+light = 18 kv-tiles per CU.
// ---------------------------------------------------------------------------
__global__ __launch_bounds__(256, 2) void attn_mfma(
    const unsigned short* __restrict__ qR, const unsigned short* __restrict__ kR,
    const unsigned short* __restrict__ vTd, unsigned short* __restrict__ ctx) {
  __shared__ unsigned short lds[32768];   // K dbuf @0/8192, V dbuf @16384/24576
  __shared__ unsigned short Ps[4][16][72];
  const int n = blockIdx.x;
  const int qp = (n < 256) ? (7 - (n >> 6)) : ((n - 256) >> 6);
  const int hb = n & 63;
  const int h = hb >> 2, b = hb & 3;
  const int tid = threadIdx.x, wid = tid >> 6, lane = tid & 63;
  const int c = lane & 15, g = lane >> 4, cg7 = c & 7;
  const long bh = (long)(b * Hn + h);
  const unsigned short* kbase = kR + bh * Sn * DHn;
  const unsigned short* vbase = vTd + bh * DHn * Sn;

  short8 qf[2][4];
#pragma unroll
  for (int sub = 0; sub < 2; ++sub) {
    const unsigned short* qrow =
        qR + (bh * Sn + qp * 128 + sub * 64 + wid * 16 + c) * DHn;
#pragma unroll
    for (int kc = 0; kc < 4; ++kc)
      qf[sub][kc] = *reinterpret_cast<const short8*>(qrow + kc * 32 + g * 8);
  }

  auto STAGE = [&](int kt, int buf) {
#pragma unroll
    for (int j = 0; j < 4; ++j) {  // K tile [64][128]
      const int ch = j * 256 + tid;
      const int r = ch >> 4, wd = ch & 15;
      const int ws = (wd & 8) | ((wd & 7) ^ (r & 7));
      gload16(kbase + (long)kt * 8192 + r * 128 + ws * 8,
              lds + buf * 8192 + j * 2048 + wid * 512);
    }
#pragma unroll
    for (int j = 0; j < 4; ++j) {  // V^T tile [128][64]
      const int ch = j * 256 + tid;
      const int d = ch >> 3, sw = ch & 7;
      gload16(vbase + (long)d * Sn + kt * 64 + ((sw ^ (d & 7)) << 3),
              lds + 16384 + buf * 8192 + j * 2048 + wid * 512);
    }
  };

  float m[2] = {-INFINITY, -INFINITY}, lsum[2] = {0.f, 0.f};
  float4v otA[8], otB[8];
#pragma unroll
  for (int fd = 0; fd < 8; ++fd) {
    otA[fd] = (float4v){0.f, 0.f, 0.f, 0.f};
    otB[fd] = (float4v){0.f, 0.f, 0.f, 0.f};
  }

  const int ntt = 2 * qp + 2;
  STAGE(0, 0);
  __syncthreads();
  int cur = 0;

  for (int kt = 0; kt < ntt; ++kt) {
    if (kt + 1 < ntt) STAGE(kt + 1, cur ^ 1);

#pragma unroll
    for (int sub = 0; sub < 2; ++sub) {
      if (sub == 0 && kt == ntt - 1) continue;
      float4v* ot = (sub == 0) ? otA : otB;

      float4v scv[4];
#pragma unroll
      for (int f = 0; f < 4; ++f) scv[f] = (float4v){0.f, 0.f, 0.f, 0.f};
      __builtin_amdgcn_s_setprio(1);
#pragma unroll
      for (int f = 0; f < 4; ++f)
#pragma unroll
        for (int kc = 0; kc < 4; ++kc) {
          const int wp = kc * 4 + g;
          const int ws = (wp & 8) | ((wp & 7) ^ cg7);
          short8 kf = *reinterpret_cast<const short8*>(
              lds + cur * 8192 + (f * 16 + c) * 128 + ws * 8);
          scv[f] = __builtin_amdgcn_mfma_f32_16x16x32_bf16(kf, qf[sub][kc],
                                                           scv[f], 0, 0, 0);
        }
      __builtin_amdgcn_s_setprio(0);

      if (kt == 2 * qp + sub) {
        const int qloc = wid * 16 + c;
#pragma unroll
        for (int f = 0; f < 4; ++f)
#pragma unroll
          for (int j = 0; j < 4; ++j)
            if (f * 16 + g * 4 + j > qloc) scv[f][j] = -INFINITY;
      }

      float tmax = -INFINITY;
#pragma unroll
      for (int f = 0; f < 4; ++f)
#pragma unroll
        for (int j = 0; j < 4; ++j) tmax = fmaxf(tmax, scv[f][j]);
      tmax = fmaxf(tmax, __shfl_xor(tmax, 16));
      tmax = fmaxf(tmax, __shfl_xor(tmax, 32));

      float mnew, corr;
      if (__all(tmax <= m[sub] + 8.f)) {  // defer-max
        mnew = m[sub]; corr = 1.f;
      } else {
        mnew = fmaxf(m[sub], tmax);
        corr = exp2f(m[sub] - mnew);
#pragma unroll
        for (int fd = 0; fd < 8; ++fd) ot[fd] *= corr;
      }
      float psum = 0.f;
#pragma unroll
      for (int f = 0; f < 4; ++f)
#pragma unroll
        for (int j = 0; j < 4; ++j) {
          scv[f][j] = exp2f(scv[f][j] - mnew);
          psum += scv[f][j];
        }
      psum += __shfl_xor(psum, 16);
      psum += __shfl_xor(psum, 32);
      lsum[sub] = lsum[sub] * corr + psum;
      m[sub] = mnew;

#pragma unroll
      for (int f = 0; f < 4; ++f) {
        unsigned int lo = (unsigned)f2bf(scv[f][0]) | ((unsigned)f2bf(scv[f][1]) << 16);
        unsigned int hi = (unsigned)f2bf(scv[f][2]) | ((unsigned)f2bf(scv[f][3]) << 16);
        uint2 pk; pk.x = lo; pk.y = hi;
        *reinterpret_cast<uint2*>(&Ps[wid][c][f * 16 + g * 4]) = pk;
      }

      short8 pf0 = *reinterpret_cast<const short8*>(&Ps[wid][c][g * 8]);
      short8 pf1 = *reinterpret_cast<const short8*>(&Ps[wid][c][32 + g * 8]);
      __builtin_amdgcn_s_setprio(1);
#pragma unroll
      for (int fd = 0; fd < 8; ++fd) {
        short8 vf0 = *reinterpret_cast<const short8*>(
            lds + 16384 + cur * 8192 + (fd * 16 + c) * 64 + ((g ^ cg7) << 3));
        short8 vf1 = *reinterpret_cast<const short8*>(
            lds + 16384 + cur * 8192 + (fd * 16 + c) * 64 + (((g + 4) ^ cg7) << 3));
        ot[fd] = __builtin_amdgcn_mfma_f32_16x16x32_bf16(vf0, pf0, ot[fd], 0, 0, 0);
        ot[fd] = __builtin_amdgcn_mfma_f32_16x16x32_bf16(vf1, pf1, ot[fd], 0, 0, 0);
      }
      __builtin_amdgcn_s_setprio(0);
    }

    __syncthreads();
    cur ^= 1;
  }

#pragma unroll
  for (int sub = 0; sub < 2; ++sub) {
    const float4v* ot = (sub == 0) ? otA : otB;
    const float inv = 1.0f / lsum[sub];
    unsigned short* orow =
        ctx + (long)(b * Sn + qp * 128 + sub * 64 + wid * 16 + c) * Dn + h * DHn;
#pragma unroll
    for (int fd = 0; fd < 8; ++fd) {
      const int d = fd * 16 + g * 4;
      uint2 pk;
      pk.x = (unsigned)f2bf(ot[fd][0] * inv) | ((unsigned)f2bf(ot[fd][1] * inv) << 16);
      pk.y = (unsigned)f2bf(ot[fd][2] * inv) | ((unsigned)f2bf(ot[fd][3] * inv) << 16);
      *reinterpret_cast<uint2*>(orow + d) = pk;
    }
  }
}

// ---------------------------------------------------------------------------
extern "C" void kernel_launch(void* const* d_in, const int* in_sizes, int n_in,
                              void* d_out, int out_size, void* d_ws, size_t ws_size,
                              hipStream_t stream) {
  const float* x     = (const float*)d_in[0];
  const float* w_qkv = (const float*)d_in[1];
  const float* w_out = (const float*)d_in[2];
  const float* rope  = (const float*)d_in[3];
  const int*   tpos  = (const int*)d_in[4];
  float* out = (float*)d_out;

  unsigned short* x16    = (unsigned short*)d_ws;
  unsigned short* wqkvT  = x16 + (size_t)BS * Dn;
  unsigned short* woutT  = wqkvT + (size_t)Dn * QKVC;
  unsigned short* qR     = woutT + (size_t)Dn * Dn;
  unsigned short* kR     = qR + (size_t)BS * Dn;
  unsigned short* vT16   = kR + (size_t)BS * Dn;
  unsigned short* ctx16  = vT16 + (size_t)BS * Dn;

  prep_all<<<8192, 256, 0, stream>>>(x, w_qkv, w_out, x16, wqkvT, woutT);
  {
    dim3 grid(BS / 128, QKVC / 128);  // 32 x 48 = 1536 = 3.0 rounds @ 2/CU
    gemm_qkv<<<grid, 256, 0, stream>>>(x16, wqkvT, rope, tpos, qR, kR, vT16, Dn);
  }
  attn_mfma<<<512, 256, 0, stream>>>(qR, kR, vT16, ctx16);
  {
    dim3 grid(BS / 128, Dn / 128);    // 32 x 16 = 512 = 1.0 round @ 2/CU
    gemm_out<<<grid, 256, 0, stream>>>(ctx16, woutT, out, Dn, Dn);
  }
}